// Round 7
// baseline (421.087 us; speedup 1.0000x reference)
//
#include <hip/hip_runtime.h>

#define TOTAL 524288
#define NSEG  16384

// ---------------------------------------------------------------------------
// Kernel 1: phi MLP (8->64 relu, 64->64 relu, 64->64) per row, then
// wave-level segmented suffix-sum (ids are sorted) + atomics from run heads.
// Thread-per-row; all h arrays fully unrolled so they live in VGPRs.
// Weights are uniform across lanes -> compiler emits s_load + v_fmac(v,s,v).
// ---------------------------------------------------------------------------
__global__ __launch_bounds__(256, 2) void phi_pool_kernel(
    const float* __restrict__ x,      // [TOTAL, 8]
    const int*   __restrict__ seg,    // [TOTAL] sorted
    const float* __restrict__ W1, const float* __restrict__ b1,   // [8,64],[64]
    const float* __restrict__ W2, const float* __restrict__ b2,   // [64,64],[64]
    const float* __restrict__ W3, const float* __restrict__ b3,   // [64,64],[64]
    float* __restrict__ pooled)       // [NSEG, 64] (pre-zeroed)
{
    const int r = blockIdx.x * 256 + threadIdx.x;

    // issue both VMEM loads (row + segment id) before the long FMA body
    const int s = seg[r];

    float xr[8];
    const float4* xp = reinterpret_cast<const float4*>(x + (size_t)r * 8);
    float4 a0 = xp[0], a1 = xp[1];
    xr[0] = a0.x; xr[1] = a0.y; xr[2] = a0.z; xr[3] = a0.w;
    xr[4] = a1.x; xr[5] = a1.y; xr[6] = a1.z; xr[7] = a1.w;

    // ---- layer 1: 8 -> 64, relu ----
    float h1[64];
#pragma unroll
    for (int j = 0; j < 64; ++j) h1[j] = b1[j];
#pragma unroll
    for (int k = 0; k < 8; ++k) {
        const float a = xr[k];
#pragma unroll
        for (int j = 0; j < 64; ++j) h1[j] = fmaf(a, W1[k * 64 + j], h1[j]);
    }
#pragma unroll
    for (int j = 0; j < 64; ++j) h1[j] = fmaxf(h1[j], 0.0f);

    // ---- layer 2: 64 -> 64, relu ----
    float h2[64];
#pragma unroll
    for (int j = 0; j < 64; ++j) h2[j] = b2[j];
#pragma unroll
    for (int k = 0; k < 64; ++k) {
        const float a = h1[k];
#pragma unroll
        for (int j = 0; j < 64; ++j) h2[j] = fmaf(a, W2[k * 64 + j], h2[j]);
    }
#pragma unroll
    for (int j = 0; j < 64; ++j) h2[j] = fmaxf(h2[j], 0.0f);

    // ---- layer 3: 64 -> 64 (no relu) ----
    float h3[64];
#pragma unroll
    for (int j = 0; j < 64; ++j) h3[j] = b3[j];
#pragma unroll
    for (int k = 0; k < 64; ++k) {
        const float a = h2[k];
#pragma unroll
        for (int j = 0; j < 64; ++j) h3[j] = fmaf(a, W3[k * 64 + j], h3[j]);
    }

    // ---- wave-level segmented suffix sum over sorted ids ----
    // Invariant after stride d: lane i holds sum over [i, min(i+2d-1, run end)].
    const int lane = threadIdx.x & 63;

#pragma unroll
    for (int d = 1; d < 64; d <<= 1) {
        const int  sd = __shfl_down(s, d);
        const bool ok = (lane + d < 64) && (sd == s);
#pragma unroll
        for (int j = 0; j < 64; ++j) {
            const float o = __shfl_down(h3[j], d);  // all lanes participate
            if (ok) h3[j] += o;                     // exec-masked add
        }
    }

    // run head (first row of its segment within this wave) commits the run sum
    const int  sprev = __shfl_up(s, 1);
    const bool head  = (lane == 0) || (sprev != s);
    if (head) {
        float* p = pooled + (size_t)s * 64;
#pragma unroll
        for (int j = 0; j < 64; ++j) atomicAdd(p + j, h3[j]);
    }
}

// ---------------------------------------------------------------------------
// Kernel 2: rho MLP (64->64 relu, 64->64 relu, 64->4) per pooled row.
// One wave per block, 256 blocks -> one per CU.
// ---------------------------------------------------------------------------
__global__ __launch_bounds__(64, 2) void rho_kernel(
    const float* __restrict__ pooled,  // [NSEG, 64]
    const float* __restrict__ W1, const float* __restrict__ b1,   // [64,64],[64]
    const float* __restrict__ W2, const float* __restrict__ b2,   // [64,64],[64]
    const float* __restrict__ W3, const float* __restrict__ b3,   // [64,4],[4]
    float* __restrict__ out)           // [NSEG, 4]
{
    const int r = blockIdx.x * 64 + threadIdx.x;

    float h0[64];
    const float4* pp = reinterpret_cast<const float4*>(pooled + (size_t)r * 64);
#pragma unroll
    for (int q = 0; q < 16; ++q) {
        float4 v = pp[q];
        h0[4 * q + 0] = v.x; h0[4 * q + 1] = v.y;
        h0[4 * q + 2] = v.z; h0[4 * q + 3] = v.w;
    }

    float h1[64];
#pragma unroll
    for (int j = 0; j < 64; ++j) h1[j] = b1[j];
#pragma unroll
    for (int k = 0; k < 64; ++k) {
        const float a = h0[k];
#pragma unroll
        for (int j = 0; j < 64; ++j) h1[j] = fmaf(a, W1[k * 64 + j], h1[j]);
    }
#pragma unroll
    for (int j = 0; j < 64; ++j) h1[j] = fmaxf(h1[j], 0.0f);

    float h2[64];
#pragma unroll
    for (int j = 0; j < 64; ++j) h2[j] = b2[j];
#pragma unroll
    for (int k = 0; k < 64; ++k) {
        const float a = h1[k];
#pragma unroll
        for (int j = 0; j < 64; ++j) h2[j] = fmaf(a, W2[k * 64 + j], h2[j]);
    }
#pragma unroll
    for (int j = 0; j < 64; ++j) h2[j] = fmaxf(h2[j], 0.0f);

    float o4[4];
#pragma unroll
    for (int j = 0; j < 4; ++j) o4[j] = b3[j];
#pragma unroll
    for (int k = 0; k < 64; ++k) {
        const float a = h2[k];
#pragma unroll
        for (int j = 0; j < 4; ++j) o4[j] = fmaf(a, W3[k * 4 + j], o4[j]);
    }

    float4* op = reinterpret_cast<float4*>(out + (size_t)r * 4);
    *op = make_float4(o4[0], o4[1], o4[2], o4[3]);
}

extern "C" void kernel_launch(void* const* d_in, const int* in_sizes, int n_in,
                              void* d_out, int out_size, void* d_ws, size_t ws_size,
                              hipStream_t stream) {
    const float* neighbors = (const float*)d_in[0];
    const int*   seg       = (const int*)d_in[1];
    const float* phi_W1 = (const float*)d_in[2];
    const float* phi_b1 = (const float*)d_in[3];
    const float* phi_W2 = (const float*)d_in[4];
    const float* phi_b2 = (const float*)d_in[5];
    const float* phi_W3 = (const float*)d_in[6];
    const float* phi_b3 = (const float*)d_in[7];
    const float* rho_W1 = (const float*)d_in[8];
    const float* rho_b1 = (const float*)d_in[9];
    const float* rho_W2 = (const float*)d_in[10];
    const float* rho_b2 = (const float*)d_in[11];
    const float* rho_W3 = (const float*)d_in[12];
    const float* rho_b3 = (const float*)d_in[13];

    float* pooled = (float*)d_ws;                       // [NSEG, 64]
    float* outp   = (float*)d_out;                      // [NSEG, 4]

    // ws is re-poisoned to 0xAA before every launch -> must zero accumulator
    hipMemsetAsync(pooled, 0, (size_t)NSEG * 64 * sizeof(float), stream);

    phi_pool_kernel<<<TOTAL / 256, 256, 0, stream>>>(
        neighbors, seg, phi_W1, phi_b1, phi_W2, phi_b2, phi_W3, phi_b3, pooled);

    rho_kernel<<<NSEG / 64, 64, 0, stream>>>(
        pooled, rho_W1, rho_b1, rho_W2, rho_b2, rho_W3, rho_b3, outp);
}